// Round 2
// baseline (386.365 us; speedup 1.0000x reference)
//
#include <hip/hip_runtime.h>
#include <math.h>

#define NEGV -1e30f

constexpr int Bc = 256;          // batch
constexpr int Tc = 256;          // time
constexpr int Cc = 512;          // classes (blank = Cc-1)
constexpr int Lc = 64;           // max label length
constexpr int Sc = 2 * Lc + 1;   // 129 extended states
constexpr int PD = 8;            // prefetch depth (rows ahead)

// One block per batch element, 256 threads (4 waves).
// Each thread owns 2 classes (float2). Per timestep:
//   - row t is in rowbuf[p] (LDS) and its exp-partials in part[p]
//   - state threads (tid < Sc) compute lse, gather emit, update alpha
//   - all threads stage row t+1 (from the register prefetch queue) into
//     rowbuf[p^1]/part[p^1], and issue the global load for row t+1+PD
// One __syncthreads per timestep.
__global__ __launch_bounds__(256) void ctc_fused_k(const float* __restrict__ logits,
                                                   const int* __restrict__ labels,
                                                   const int* __restrict__ lab_len,
                                                   const int* __restrict__ log_len,
                                                   float* __restrict__ nll_out) {
    const int b   = blockIdx.x;
    const int tid = threadIdx.x;
    const int wid = tid >> 6;
    const int lane = tid & 63;

    __shared__ float rowbuf[2][Cc];
    __shared__ float part[2][4];
    __shared__ float alpha[2][Sc];
    __shared__ float fin[2];

    const int ll  = log_len[b];
    const int end = 2 * lab_len[b];

    const bool st = (tid < Sc);
    int  y = Cc - 1;          // blank for even s
    bool skip = false;
    if (st && (tid & 1)) {
        y = labels[b * Lc + (tid >> 1)];
        if (tid >= 3) skip = (y != labels[b * Lc + (tid >> 1) - 1]);
    }

    const float* lb = logits + (size_t)b * Tc * Cc;

    // ---- prologue: fill the prefetch queue with rows 0..PD-1 ----
    float2 xq[PD];
#pragma unroll
    for (int d = 0; d < PD; ++d)
        xq[d] = ((const float2*)(lb + (size_t)d * Cc))[tid];

    if (tid < 2) fin[tid] = NEGV;

    // stage row 0 into buffer 0
    {
        float2 x = xq[0];
        ((float2*)rowbuf[0])[tid] = x;
        float e = __expf(x.x) + __expf(x.y);
#pragma unroll
        for (int o = 32; o; o >>= 1) e += __shfl_xor(e, o, 64);
        if (lane == 0) part[0][wid] = e;
    }
    // rotate queue; issue load for row PD
#pragma unroll
    for (int d = 0; d < PD - 1; ++d) xq[d] = xq[d + 1];
    xq[PD - 1] = ((const float2*)(lb + (size_t)(PD < Tc ? PD : Tc - 1) * Cc))[tid];

    int p = 0;
    for (int t = 0; t < Tc; ++t) {
        __syncthreads();   // rowbuf[p], part[p], alpha[p^1] (= alpha_{t-1}) visible

        // ---- consume time t ----
        if (st) {
            float lse  = __logf(part[p][0] + part[p][1] + part[p][2] + part[p][3]);
            float emit = rowbuf[p][y] - lse;
            float na;
            if (t == 0) {
                na = (tid <= 1) ? emit : NEGV;
            } else {
                float a0 = alpha[p ^ 1][tid];
                float a1 = (tid >= 1) ? alpha[p ^ 1][tid - 1] : NEGV;
                float a2 = skip ? alpha[p ^ 1][tid - 2] : NEGV;
                float m  = fmaxf(fmaxf(a0, a1), a2);
                na = m + __logf(__expf(a0 - m) + __expf(a1 - m) + __expf(a2 - m)) + emit;
            }
            alpha[p][tid] = na;
            if (t == ll - 1) {
                if (tid == end)          fin[0] = na;
                else if (tid == end - 1) fin[1] = na;
            }
        }

        // ---- stage time t+1 into buffer p^1 ----
        if (t + 1 < Tc) {
            float2 x = xq[0];
            ((float2*)rowbuf[p ^ 1])[tid] = x;
            float e = __expf(x.x) + __expf(x.y);
#pragma unroll
            for (int o = 32; o; o >>= 1) e += __shfl_xor(e, o, 64);
            if (lane == 0) part[p ^ 1][wid] = e;
#pragma unroll
            for (int d = 0; d < PD - 1; ++d) xq[d] = xq[d + 1];
            int tl = t + 1 + PD; tl = (tl < Tc) ? tl : Tc - 1;
            xq[PD - 1] = ((const float2*)(lb + (size_t)tl * Cc))[tid];
        }
        p ^= 1;
    }

    __syncthreads();
    if (tid == 0) {
        float m   = fmaxf(fin[0], fin[1]);
        float nll = -(m + __logf(__expf(fin[0] - m) + __expf(fin[1] - m)));
        nll_out[b] = nll;
    }
}

// Single block: mean of the 256 per-batch NLLs.
__global__ __launch_bounds__(256) void reduce_k(const float* __restrict__ nll,
                                                float* __restrict__ out) {
    int tid = threadIdx.x;
    float v = nll[tid];
#pragma unroll
    for (int o = 32; o; o >>= 1) v += __shfl_xor(v, o, 64);
    __shared__ float pr[4];
    if ((tid & 63) == 0) pr[tid >> 6] = v;
    __syncthreads();
    if (tid == 0) out[0] = (pr[0] + pr[1] + pr[2] + pr[3]) * (1.0f / Bc);
}

extern "C" void kernel_launch(void* const* d_in, const int* in_sizes, int n_in,
                              void* d_out, int out_size, void* d_ws, size_t ws_size,
                              hipStream_t stream) {
    const float* logits  = (const float*)d_in[0];
    const int*   labels  = (const int*)d_in[1];
    const int*   lab_len = (const int*)d_in[2];
    const int*   log_len = (const int*)d_in[3];
    float* out = (float*)d_out;
    float* nll = (float*)d_ws;   // Bc floats

    hipLaunchKernelGGL(ctc_fused_k, dim3(Bc), dim3(256), 0, stream,
                       logits, labels, lab_len, log_len, nll);
    hipLaunchKernelGGL(reduce_k, dim3(1), dim3(256), 0, stream, nll, out);
}

// Round 3
// 305.406 us; speedup vs baseline: 1.2651x; 1.2651x over previous
//
#include <hip/hip_runtime.h>
#include <math.h>

#define NEGV -1e30f

constexpr int Bc = 256;          // batch
constexpr int Tc = 256;          // time
constexpr int Cc = 512;          // classes (blank = Cc-1)
constexpr int Lc = 64;           // max label length
constexpr int EP = 68;           // emission row: [0]=blank, [1..64]=labels, pad to 68 (16B-aligned)
constexpr int PD = 8;            // prefetch depth (timesteps ahead), Tc % PD == 0

// ---------------------------------------------------------------------------
// Phase 1 (parallel, BW-bound): per (b,t) compute lse over C=512 and emit the
// compact emission row: blank + the 64 label-class log-probs.
// grid = B*T/4 blocks x 256 threads; wave w handles t = t0 + w.
// ---------------------------------------------------------------------------
__global__ __launch_bounds__(256) void emit_k(const float* __restrict__ logits,
                                              const int* __restrict__ labels,
                                              float* __restrict__ ebuf) {
    const int blk  = blockIdx.x;
    const int b    = blk >> 6;                       // / (Tc/4)
    const int w    = threadIdx.x >> 6;
    const int t    = ((blk & 63) << 2) + w;
    const int lane = threadIdx.x & 63;

    __shared__ float rows[4][Cc];

    const float4* r4 = (const float4*)(logits + ((size_t)b * Tc + t) * Cc);
    float4 x0 = r4[lane];
    float4 x1 = r4[lane + 64];
    ((float4*)rows[w])[lane]      = x0;
    ((float4*)rows[w])[lane + 64] = x1;

    // logits ~ N(0,1): exp without max-subtraction is safe (verified absmax 0.0)
    float e = __expf(x0.x) + __expf(x0.y) + __expf(x0.z) + __expf(x0.w)
            + __expf(x1.x) + __expf(x1.y) + __expf(x1.z) + __expf(x1.w);
#pragma unroll
    for (int o = 32; o; o >>= 1) e += __shfl_xor(e, o, 64);
    float lse = __logf(e);

    int y = labels[b * Lc + lane];
    __syncthreads();   // cheap (once per block); guarantees LDS row visible

    float lab_em = rows[w][y] - lse;
    float* orow = ebuf + ((size_t)b * Tc + t) * EP;
    orow[1 + lane] = lab_em;
    if (lane == 0) orow[0] = rows[w][Cc - 1] - lse;
}

// ---------------------------------------------------------------------------
// Phase 2 (serial, register-resident): one wave per batch element.
// Lane l owns extended states s=2l (blank) and s=2l+1 (label l); lane 63 also
// owns s=128 (blank, lane-local update). One shfl_up per timestep.
// Emissions prefetched PD steps ahead via statically-indexed ring (no rotation).
// ---------------------------------------------------------------------------
__global__ __launch_bounds__(64) void alpha_k(const float* __restrict__ ebuf,
                                              const int* __restrict__ labels,
                                              const int* __restrict__ lab_len,
                                              const int* __restrict__ log_len,
                                              float* __restrict__ nll) {
    const int b = blockIdx.x;
    const int l = threadIdx.x;                       // lane
    const float* eb = ebuf + (size_t)b * Tc * EP;

    const int mylab   = labels[b * Lc + l];
    const int prevlab = (l > 0) ? labels[b * Lc + l - 1] : -1;
    const bool skip   = (l >= 1) && (mylab != prevlab);
    const int llm1 = log_len[b] - 1;
    const int end  = 2 * lab_len[b];

    float bq[PD], lq[PD];
#pragma unroll
    for (int d = 0; d < PD; ++d) {
        bq[d] = eb[(size_t)d * EP];
        lq[d] = eb[(size_t)d * EP + 1 + l];
    }

    float ae = NEGV, ao = NEGV, ax = NEGV;          // alpha[2l], alpha[2l+1], alpha[128]
    float fe = NEGV, fo = NEGV, fx = NEGV;          // snapshot at t = ll-1

    for (int tb = 0; tb < Tc; tb += PD) {
#pragma unroll
        for (int d = 0; d < PD; ++d) {
            const int t = tb + d;
            const float em_b = bq[d];                // wave-uniform (blank)
            const float em_l = lq[d];
            if (t == 0) {
                ae = (l == 0) ? em_b : NEGV;
                ao = (l == 0) ? em_l : NEGV;
                ax = NEGV;
            } else {
                float po = __shfl_up(ao, 1, 64);     // alpha[2l-1]
                if (l == 0) po = NEGV;
                float o63 = __shfl(ao, 63, 64);      // alpha[127] (for s=128)

                // s = 2l (blank): logaddexp(alpha[2l], alpha[2l-1]) + em_b
                float m0  = fmaxf(ae, po);
                float nae = m0 + __logf(__expf(ae - m0) + __expf(po - m0)) + em_b;

                // s = 2l+1 (label l): logaddexp3(alpha[2l+1], alpha[2l], skip?alpha[2l-1]) + em_l
                float a2  = skip ? po : NEGV;
                float m1  = fmaxf(fmaxf(ao, ae), a2);
                float nao = m1 + __logf(__expf(ao - m1) + __expf(ae - m1) + __expf(a2 - m1)) + em_l;

                // s = 128 (blank, lane-local on lane 63; computed uniformly, harmless)
                float m2  = fmaxf(ax, o63);
                float nax = m2 + __logf(__expf(ax - m2) + __expf(o63 - m2)) + em_b;

                ae = nae; ao = nao; ax = nax;
            }
            if (t == llm1) { fe = ae; fo = ao; fx = ax; }

            const int tn = t + PD;                   // refill slot d (static index)
            if (tn < Tc) {
                bq[d] = eb[(size_t)tn * EP];
                lq[d] = eb[(size_t)tn * EP + 1 + l];
            }
        }
    }

    float f0 = (end >= 128) ? __shfl(fx, 63, 64) : __shfl(fe, end >> 1, 64);
    float f1 = __shfl(fo, (end >> 1) - 1, 64);
    float m  = fmaxf(f0, f1);
    float res = -(m + __logf(__expf(f0 - m) + __expf(f1 - m)));
    if (l == 0) nll[b] = res;
}

// Single block: mean of the 256 per-batch NLLs.
__global__ __launch_bounds__(256) void reduce_k(const float* __restrict__ nll,
                                                float* __restrict__ out) {
    int tid = threadIdx.x;
    float v = nll[tid];
#pragma unroll
    for (int o = 32; o; o >>= 1) v += __shfl_xor(v, o, 64);
    __shared__ float pr[4];
    if ((tid & 63) == 0) pr[tid >> 6] = v;
    __syncthreads();
    if (tid == 0) out[0] = (pr[0] + pr[1] + pr[2] + pr[3]) * (1.0f / Bc);
}

extern "C" void kernel_launch(void* const* d_in, const int* in_sizes, int n_in,
                              void* d_out, int out_size, void* d_ws, size_t ws_size,
                              hipStream_t stream) {
    const float* logits  = (const float*)d_in[0];
    const int*   labels  = (const int*)d_in[1];
    const int*   lab_len = (const int*)d_in[2];
    const int*   log_len = (const int*)d_in[3];
    float* out  = (float*)d_out;
    float* nll  = (float*)d_ws;                          // 256 floats
    float* ebuf = (float*)((char*)d_ws + 1024);          // B*T*EP floats = 17.8 MB

    hipLaunchKernelGGL(emit_k, dim3(Bc * Tc / 4), dim3(256), 0, stream,
                       logits, labels, ebuf);
    hipLaunchKernelGGL(alpha_k, dim3(Bc), dim3(64), 0, stream,
                       ebuf, labels, lab_len, log_len, nll);
    hipLaunchKernelGGL(reduce_k, dim3(1), dim3(256), 0, stream, nll, out);
}

// Round 4
// 256.564 us; speedup vs baseline: 1.5059x; 1.1904x over previous
//
#include <hip/hip_runtime.h>
#include <math.h>

#define NEGV -1e30f

constexpr int Bc = 256;          // batch
constexpr int Tc = 256;          // time
constexpr int Cc = 512;          // classes (blank = Cc-1)
constexpr int Lc = 64;           // max label length
constexpr int EP = 68;           // emission row: [0]=blank, [1..64]=labels, pad to 68 (16B-aligned)

// ---------------------------------------------------------------------------
// Phase 1 (parallel, BW-bound): per (b,t) compute lse over C=512 and emit the
// compact emission row: blank + the 64 label-class log-probs.
// grid = B*T/4 blocks x 256 threads; wave w handles t = t0 + w.
// ---------------------------------------------------------------------------
__global__ __launch_bounds__(256) void emit_k(const float* __restrict__ logits,
                                              const int* __restrict__ labels,
                                              float* __restrict__ ebuf) {
    const int blk  = blockIdx.x;
    const int b    = blk >> 6;                       // / (Tc/4)
    const int w    = threadIdx.x >> 6;
    const int t    = ((blk & 63) << 2) + w;
    const int lane = threadIdx.x & 63;

    __shared__ float rows[4][Cc];

    const float4* r4 = (const float4*)(logits + ((size_t)b * Tc + t) * Cc);
    float4 x0 = r4[lane];
    float4 x1 = r4[lane + 64];
    ((float4*)rows[w])[lane]      = x0;
    ((float4*)rows[w])[lane + 64] = x1;

    // logits ~ N(0,1): exp without max-subtraction is safe (verified absmax 0.0)
    float e = __expf(x0.x) + __expf(x0.y) + __expf(x0.z) + __expf(x0.w)
            + __expf(x1.x) + __expf(x1.y) + __expf(x1.z) + __expf(x1.w);
#pragma unroll
    for (int o = 32; o; o >>= 1) e += __shfl_xor(e, o, 64);
    float lse = __logf(e);

    int y = labels[b * Lc + lane];
    __syncthreads();   // once per block; LDS row visible to gathering lanes

    float lab_em = rows[w][y] - lse;
    float* orow = ebuf + ((size_t)b * Tc + t) * EP;
    orow[1 + lane] = lab_em;
    if (lane == 0) orow[0] = rows[w][Cc - 1] - lse;
}

// ---------------------------------------------------------------------------
// Phase 2 (serial): one block per batch element. All 4 waves stage the
// batch's full emission slice (Tc*EP floats = 69.6 KB) into LDS with
// coalesced float4 loads; then wave 0 runs the register-resident recurrence.
// Lane l owns states 2l (blank) and 2l+1 (label l); lane 63 also owns s=128
// (lane-local: alpha[127] is lane 63's own ao). One shfl_up per timestep.
// Emissions prefetched 2 steps ahead from LDS in NAMED scalars (no arrays ->
// nothing the compiler can demote to scratch).
// ---------------------------------------------------------------------------
__global__ __launch_bounds__(256) void alpha_k(const float* __restrict__ ebuf,
                                               const int* __restrict__ labels,
                                               const int* __restrict__ lab_len,
                                               const int* __restrict__ log_len,
                                               float* __restrict__ nll) {
    const int b   = blockIdx.x;
    const int tid = threadIdx.x;

    __shared__ float E[Tc * EP];   // 69,632 bytes

    {   // bulk copy: 4352 float4s over 256 threads = 17 iterations, pipelined
        const float4* src = (const float4*)(ebuf + (size_t)b * Tc * EP);
        float4* dst = (float4*)E;
#pragma unroll
        for (int i = 0; i < (Tc * EP / 4) / 256; ++i)
            dst[tid + i * 256] = src[tid + i * 256];
    }
    __syncthreads();
    if (tid >= 64) return;         // waves 1-3 done; no barriers after this

    const int l = tid;
    const int mylab   = labels[b * Lc + l];
    const int prevlab = (l > 0) ? labels[b * Lc + l - 1] : -1;
    const bool skip   = (l >= 1) && (mylab != prevlab);
    const int llm1 = log_len[b] - 1;
    const int end  = 2 * lab_len[b];

    float ae, ao, ax;              // alpha[2l], alpha[2l+1], alpha[128]
    float fe = NEGV, fo = NEGV, fx = NEGV;

    // t = 0
    {
        float b0 = E[0], l0 = E[1 + l];
        ae = (l == 0) ? b0 : NEGV;
        ao = (l == 0) ? l0 : NEGV;
        ax = NEGV;
        if (llm1 == 0) { fe = ae; fo = ao; fx = ax; }
    }

    // depth-2 LDS prefetch in named scalars
    float cb = E[EP],     cl = E[EP + 1 + l];          // t = 1
    float nb = E[2 * EP], nl = E[2 * EP + 1 + l];      // t = 2

    for (int t = 1; t < Tc; ++t) {
        const float pb = cb, pl = cl;                  // consume t
        cb = nb; cl = nl;                              // shift
        int tp = t + 2; tp = (tp < Tc) ? tp : Tc - 1;  // prefetch t+2 (clamped)
        nb = E[tp * EP];
        nl = E[tp * EP + 1 + l];

        float po = __shfl_up(ao, 1, 64);               // alpha[2l-1]
        if (l == 0) po = NEGV;

        // s = 2l (blank)
        float m0  = fmaxf(ae, po);
        float nae = m0 + __logf(__expf(ae - m0) + __expf(po - m0)) + pb;

        // s = 2l+1 (label l)
        float a2  = skip ? po : NEGV;
        float m1  = fmaxf(fmaxf(ao, ae), a2);
        float nao = m1 + __logf(__expf(ao - m1) + __expf(ae - m1) + __expf(a2 - m1)) + pl;

        // s = 128 (blank; alpha[127] == own ao on lane 63, others compute garbage)
        float m2  = fmaxf(ax, ao);
        float nax = m2 + __logf(__expf(ax - m2) + __expf(ao - m2)) + pb;

        ae = nae; ao = nao; ax = nax;
        if (t == llm1) { fe = ae; fo = ao; fx = ax; }
    }

    float f0 = (end >= 128) ? __shfl(fx, 63, 64) : __shfl(fe, end >> 1, 64);
    float f1 = __shfl(fo, (end >> 1) - 1, 64);
    float m  = fmaxf(f0, f1);
    float res = -(m + __logf(__expf(f0 - m) + __expf(f1 - m)));
    if (l == 0) nll[b] = res;
}

// Single block: mean of the 256 per-batch NLLs.
__global__ __launch_bounds__(256) void reduce_k(const float* __restrict__ nll,
                                                float* __restrict__ out) {
    int tid = threadIdx.x;
    float v = nll[tid];
#pragma unroll
    for (int o = 32; o; o >>= 1) v += __shfl_xor(v, o, 64);
    __shared__ float pr[4];
    if ((tid & 63) == 0) pr[tid >> 6] = v;
    __syncthreads();
    if (tid == 0) out[0] = (pr[0] + pr[1] + pr[2] + pr[3]) * (1.0f / Bc);
}

extern "C" void kernel_launch(void* const* d_in, const int* in_sizes, int n_in,
                              void* d_out, int out_size, void* d_ws, size_t ws_size,
                              hipStream_t stream) {
    const float* logits  = (const float*)d_in[0];
    const int*   labels  = (const int*)d_in[1];
    const int*   lab_len = (const int*)d_in[2];
    const int*   log_len = (const int*)d_in[3];
    float* out  = (float*)d_out;
    float* nll  = (float*)d_ws;                          // 256 floats
    float* ebuf = (float*)((char*)d_ws + 1024);          // B*T*EP floats = 17.8 MB

    hipLaunchKernelGGL(emit_k, dim3(Bc * Tc / 4), dim3(256), 0, stream,
                       logits, labels, ebuf);
    hipLaunchKernelGGL(alpha_k, dim3(Bc), dim3(256), 0, stream,
                       ebuf, labels, lab_len, log_len, nll);
    hipLaunchKernelGGL(reduce_k, dim3(1), dim3(256), 0, stream, nll, out);
}